// Round 12
// baseline (896.550 us; speedup 1.0000x reference)
//
#include <hip/hip_runtime.h>
#include <hip/hip_bf16.h>

#define TOKENS 32768
#define NEXP   16
#define HID    2048
#define IMD    1408
#define BM 256
#define BK 64

typedef __bf16 bf16x8 __attribute__((ext_vector_type(8)));
typedef float  f32x4  __attribute__((ext_vector_type(4)));
typedef unsigned short u16x8 __attribute__((ext_vector_type(8)));

using gptr1_t = const __attribute__((address_space(1))) void*;
using lptr3_t = __attribute__((address_space(3))) void*;

static __device__ __forceinline__ unsigned short f2bf(float f) {
  unsigned int x = __builtin_bit_cast(unsigned int, f);
  x += 0x7fffu + ((x >> 16) & 1u);   // round-to-nearest-even
  return (unsigned short)(x >> 16);
}
static __device__ __forceinline__ void gload16(const void* g, void* l) {
  __builtin_amdgcn_global_load_lds((gptr1_t)g, (lptr3_t)l, 16, 0, 0);
}
static __device__ __forceinline__ void vwait0() {
  asm volatile("s_waitcnt vmcnt(0)" ::: "memory");
}
static __device__ __forceinline__ void lgkm(int n) {
  switch (n) {
    case 0: asm volatile("s_waitcnt lgkmcnt(0)" ::: "memory"); break;
    case 4: asm volatile("s_waitcnt lgkmcnt(4)" ::: "memory"); break;
    default: asm volatile("s_waitcnt lgkmcnt(8)" ::: "memory"); break;
  }
}
// raw LDS read: we own the lgkmcnt discipline (rule 18: sched_barrier fences)
static __device__ __forceinline__ f32x4 ds128(unsigned addr) {
  f32x4 d;
  asm volatile("ds_read_b128 %0, %1" : "=&v"(d) : "v"(addr));
  return d;
}

// ---------------- f32 -> bf16 straight convert (x) ----------------
__global__ __launch_bounds__(256)
void convert_kernel(const float* __restrict__ in, unsigned short* __restrict__ out, size_t n)
{
  size_t i = ((size_t)blockIdx.x * blockDim.x + threadIdx.x) * 8;
  if (i >= n) return;
  float4 a = *(const float4*)(in + i);
  float4 b = *(const float4*)(in + i + 4);
  u16x8 o;
  o[0] = f2bf(a.x); o[1] = f2bf(a.y); o[2] = f2bf(a.z); o[3] = f2bf(a.w);
  o[4] = f2bf(b.x); o[5] = f2bf(b.y); o[6] = f2bf(b.z); o[7] = f2bf(b.w);
  *(u16x8*)(out + i) = o;
}

// ------------- f32 [E][K][N] -> bf16 [E][N][K] transpose-convert -------------
__global__ __launch_bounds__(256)
void transpose_conv_kernel(const float* __restrict__ in, unsigned short* __restrict__ out,
                           int K, int N)
{
  __shared__ float tile[32][33];
  const int e = blockIdx.z;
  const float* ip = in + (size_t)e * K * N;
  unsigned short* op = out + (size_t)e * K * N;
  const int c0 = blockIdx.x * 32, r0 = blockIdx.y * 32;
  const int tx = threadIdx.x, ty = threadIdx.y;
#pragma unroll
  for (int i = 0; i < 4; ++i)
    tile[ty + 8 * i][tx] = ip[(size_t)(r0 + ty + 8 * i) * N + c0 + tx];
  __syncthreads();
#pragma unroll
  for (int i = 0; i < 4; ++i)
    op[(size_t)(c0 + ty + 8 * i) * K + r0 + tx] = f2bf(tile[tx][ty + 8 * i]);
}

// ==== grouped GEMM, 256x256, BK=64, 16x16x32 MFMA, asm-DS 1-barrier pipeline ==
// r6/r11 skeleton (asm ds_read + counted lgkm + 1 barrier/tile + XCD chunking)
// with r4's PROVEN-ZERO-CONFLICT fragment geometry: 16-row frags, slot =
// (kk*4+fq) ^ (fr&7) (distinct XOR per 16-lane group — the property the 32-row
// geometry lacked; r6/r11 measured 3.46e7 conflicts, r3/r4/r7 measured 0).
// Per tile, 4 half-clusters; ds outstanding <= 12 (< 15 lgkm cap); ledger:
//   issue H0(8) H1(4) | lgkm4 -> H0 | MF16 | issue H2(8) | lgkm8 -> H1 | MF16 |
//   issue H3(4) stageB | lgkm4 -> H2 | MF16 | stageA | lgkm0 -> H3 | MF16 |
//   vwait0 barrier.
// MODE 0: fused gate+up (nf0,1=gate, nf2,3=up cols): h = bf16(silu(g)*u).
// MODE 1: down: Cf = acc (f32).
template<int MODE, int K, int N>
__global__ __launch_bounds__(512, 2)
void gemm_kernel(const unsigned short* __restrict__ A,
                 const unsigned short* __restrict__ B0m,
                 const unsigned short* __restrict__ B1m,
                 unsigned short* __restrict__ Hc,
                 float* __restrict__ Cf,
                 const int* __restrict__ gs)
{
  constexpr int NRT = TOKENS / BM;   // 128 row tiles
  constexpr int nt  = K / BK;

  __shared__ __align__(16) unsigned short lA[2][256 * 64];  // 64 KiB
  __shared__ __align__(16) unsigned short lB[2][256 * 64];  // 64 KiB

  // XCD chunking (r11-proven: FETCH 811->484MB): xcd owns 16 consecutive
  // row-tiles x all column tiles; bijective (nwg/8 = 16*CTN exactly).
  const int xcd = blockIdx.x & 7;
  const int i   = blockIdx.x >> 3;
  const int rt  = xcd * (NRT / 8) + (i % (NRT / 8));
  const int ct  = i / (NRT / 8);
  const int row0 = rt * BM;

  int e = 0;
  { int a0 = 0;
    for (int ii = 0; ii < NEXP; ++ii) { int s = gs[ii]; if (row0 < a0 + s) { e = ii; break; } a0 += s; } }

  const unsigned short* Ap = A + (size_t)row0 * K;
  const unsigned short* Bg = B0m + (size_t)e * N * K;
  const unsigned short* Bu = (MODE == 0) ? (B1m + (size_t)e * N * K) : nullptr;

  const int tid  = threadIdx.x;
  const int lane = tid & 63, wave = tid >> 6;
  const int wr = wave >> 2, wc = wave & 3;   // 2 M-waves x 4 N-waves, 128x64/wave
  const int fr = lane & 15, fq = lane >> 4;
  const int r8 = lane >> 3;
  const int slog = ((lane & 7) ^ r8) * 8;    // pre-swizzled staging source column

  // conflict-free slot swizzle (r4-proven): byte off = ((kk*4+fq)^(fr&7))*16
  const unsigned c0 = (unsigned)(((0 + fq) ^ (fr & 7)) * 16);
  const unsigned c1 = (unsigned)(((4 + fq) ^ (fr & 7)) * 16);

  // LDS byte bases (low 32 bits of generic pointer = LDS offset)
  const unsigned lAb = (unsigned)(unsigned long long)(const void*)&lA[0][0];
  const unsigned lBb = (unsigned)(unsigned long long)(const void*)&lB[0][0];
  const unsigned aRowB = lAb + (unsigned)((wr * 128 + fr) * 128);  // 128B rows
  const unsigned bRowB = lBb + (unsigned)((wc * 64 + fr) * 128);

  f32x4 acc[8][4] = {};

  // stage one 128-row chunk (2 x gload16/thread) — r11 verbatim.
  auto stage = [&](int chunk, int tt) {
    const int buf = tt & 1;
    const int k0 = tt * BK;
#pragma unroll
    for (int w = 0; w < 2; ++w) {
      if (chunk >= 2) {
        const int c = chunk - 2;
        unsigned short* ldst = &lA[buf][(c * 128 + w * 64 + wave * 8) * 64];
        const int grow = c * 128 + w * 64 + wave * 8 + r8;
        gload16(Ap + (size_t)grow * K + k0 + slog, ldst);
      } else {
        unsigned short* ldst = &lB[buf][(chunk * 128 + w * 64 + wave * 8) * 64];
        const int rem = w * 64 + wave * 8 + r8;       // 0..127
        const int v = chunk * 128 + rem;              // B LDS row 0..255
        if constexpr (MODE == 0) {
          const int wcq = v >> 6, p = (v >> 5) & 1, ii = v & 31;
          const unsigned short* mb = p ? Bu : Bg;
          const int gcol = ct * 128 + wcq * 32 + ii;
          gload16(mb + (size_t)gcol * K + k0 + slog, ldst);
        } else {
          const int gcol = ct * 256 + v;
          gload16(Bg + (size_t)gcol * K + k0 + slog, ldst);
        }
      }
    }
  };

  // frag reads: A mf in 0..7 at byte aRowB + mf*2048 + c; B nf at bRowB + nf*2048 + c
  auto rdA4 = [&](f32x4* d, int mh, unsigned c, unsigned bo) {
#pragma unroll
    for (int m = 0; m < 4; ++m)
      d[m] = ds128(aRowB + bo + (unsigned)((mh * 4 + m) * 2048) + c);
  };
  auto rdB4 = [&](f32x4* d, unsigned c, unsigned bo) {
#pragma unroll
    for (int n = 0; n < 4; ++n)
      d[n] = ds128(bRowB + bo + (unsigned)(n * 2048) + c);
  };
  auto MF16 = [&](int ab, const f32x4* a4, const f32x4* b4) {
    __builtin_amdgcn_sched_barrier(0);
    __builtin_amdgcn_s_setprio(1);
#pragma unroll
    for (int m = 0; m < 4; ++m)
#pragma unroll
      for (int n = 0; n < 4; ++n)
        acc[ab + m][n] = __builtin_amdgcn_mfma_f32_16x16x32_bf16(
            __builtin_bit_cast(bf16x8, a4[m]), __builtin_bit_cast(bf16x8, b4[n]),
            acc[ab + m][n], 0, 0, 0);
    __builtin_amdgcn_s_setprio(0);
    __builtin_amdgcn_sched_barrier(0);
  };

  // prologue: tile 0 staged and published
  stage(0, 0); stage(1, 0); stage(2, 0); stage(3, 0);
  vwait0();
  __builtin_amdgcn_s_barrier();

  f32x4 a0[4], a1[4], b0[4], b1[4];

#pragma unroll 1
  for (int t = 0; t < nt; ++t) {
    const unsigned bo = (unsigned)((t & 1) * 32768);
    const bool more = (t + 1 < nt);

    rdA4(a0, 0, c0, bo); rdB4(b0, c0, bo);   // H0: 8 reads (kk0: a rows 0-63, b)
    rdA4(a1, 1, c0, bo);                     // H1: 4 reads (kk0: a rows 64-127)
    lgkm(4);                                 // H0 done (H1 in flight)
    MF16(0, a0, b0);
    rdA4(a0, 0, c1, bo); rdB4(b1, c1, bo);   // H2: 8 reads (kk1)
    lgkm(8);                                 // H1 done (H2 in flight)
    MF16(4, a1, b0);
    rdA4(a1, 1, c1, bo);                     // H3: 4 reads (kk1 second half)
    if (more) { stage(0, t + 1); stage(1, t + 1); }
    lgkm(4);                                 // H2 done (H3 in flight)
    MF16(0, a0, b1);
    if (more) { stage(2, t + 1); stage(3, t + 1); }
    lgkm(0);                                 // H3 done
    MF16(4, a1, b1);

    vwait0();                                // own t+1 stages landed
    __builtin_amdgcn_s_barrier();            // publish LDS[t+1 buffer]
  }

  // epilogue. 16x16 C/D layout (m89-verified): col = lane&15, row = fq*4 + r.
  // MODE0 frag cols: nf -> matrix nf>>1 (0=gate,1=up), col wc*32+(nf&1)*16+fr.
#pragma unroll
  for (int mi = 0; mi < 8; ++mi) {
    const int rowb = row0 + wr * 128 + ((mi >> 2) * 64) + (mi & 3) * 16 + fq * 4;
    if constexpr (MODE == 0) {
#pragma unroll
      for (int m2 = 0; m2 < 2; ++m2) {
        const int col = ct * 128 + wc * 32 + m2 * 16 + fr;
        f32x4 g = acc[mi][m2], u = acc[mi][m2 + 2];
#pragma unroll
        for (int r = 0; r < 4; ++r) {
          float gv = g[r];
          Hc[(size_t)(rowb + r) * N + col] = f2bf(gv / (1.f + __expf(-gv)) * u[r]);
        }
      }
    } else {
#pragma unroll
      for (int nf = 0; nf < 4; ++nf) {
        const int col = ct * 256 + wc * 64 + nf * 16 + fr;
        f32x4 v = acc[mi][nf];
#pragma unroll
        for (int r = 0; r < 4; ++r)
          Cf[(size_t)(rowb + r) * N + col] = v[r];
      }
    }
  }
}

extern "C" void kernel_launch(void* const* d_in, const int* in_sizes, int n_in,
                              void* d_out, int out_size, void* d_ws, size_t ws_size,
                              hipStream_t stream)
{
  const float* x  = (const float*)d_in[0];
  const float* wg = (const float*)d_in[1];
  const float* wu = (const float*)d_in[2];
  const float* wd = (const float*)d_in[3];
  const int*   gs = (const int*)d_in[4];
  float* out = (float*)d_out;

  const size_t SZ_XB = (size_t)TOKENS * HID * 2;
  const size_t SZ_W  = (size_t)NEXP * HID * IMD * 2;
  const size_t SZ_H  = (size_t)TOKENS * IMD * 2;
  if (ws_size < SZ_XB + 2 * SZ_W + SZ_H) return;

  char* ws = (char*)d_ws;
  unsigned short* xb  = (unsigned short*)ws;
  unsigned short* wTg = (unsigned short*)(ws + SZ_XB);
  unsigned short* wTu = (unsigned short*)(ws + SZ_XB + SZ_W);
  unsigned short* h   = (unsigned short*)(ws + SZ_XB + 2 * SZ_W);

  const int cvt_grid = (int)(((size_t)TOKENS * HID) / (256 * 8));
  convert_kernel<<<cvt_grid, 256, 0, stream>>>(x, xb, (size_t)TOKENS * HID);

  transpose_conv_kernel<<<dim3(IMD / 32, HID / 32, NEXP), dim3(32, 8), 0, stream>>>(wg, wTg, HID, IMD);
  transpose_conv_kernel<<<dim3(IMD / 32, HID / 32, NEXP), dim3(32, 8), 0, stream>>>(wu, wTu, HID, IMD);
  gemm_kernel<0, HID, IMD><<<(TOKENS / BM) * (IMD / 128), 512, 0, stream>>>(
      xb, wTg, wTu, h, nullptr, gs);

  transpose_conv_kernel<<<dim3(HID / 32, IMD / 32, NEXP), dim3(32, 8), 0, stream>>>(wd, wTg, IMD, HID);
  gemm_kernel<1, IMD, HID><<<(TOKENS / BM) * (HID / 256), 512, 0, stream>>>(
      h, wTg, nullptr, nullptr, out, gs);
}

// Round 13
// 862.960 us; speedup vs baseline: 1.0389x; 1.0389x over previous
//
#include <hip/hip_runtime.h>
#include <hip/hip_bf16.h>

#define TOKENS 32768
#define NEXP   16
#define HID    2048
#define IMD    1408
#define BM 256
#define BK 64

typedef __bf16 bf16x8 __attribute__((ext_vector_type(8)));
typedef float  f32x4  __attribute__((ext_vector_type(4)));
typedef float  f32x16 __attribute__((ext_vector_type(16)));
typedef unsigned short u16x8 __attribute__((ext_vector_type(8)));

using gptr1_t = const __attribute__((address_space(1))) void*;
using lptr3_t = __attribute__((address_space(3))) void*;

static __device__ __forceinline__ unsigned short f2bf(float f) {
  unsigned int x = __builtin_bit_cast(unsigned int, f);
  x += 0x7fffu + ((x >> 16) & 1u);   // round-to-nearest-even
  return (unsigned short)(x >> 16);
}
static __device__ __forceinline__ void gload16(const void* g, void* l) {
  __builtin_amdgcn_global_load_lds((gptr1_t)g, (lptr3_t)l, 16, 0, 0);
}
static __device__ __forceinline__ void vwait0() {
  asm volatile("s_waitcnt vmcnt(0)" ::: "memory");
}
static __device__ __forceinline__ void lgkm6() {
  asm volatile("s_waitcnt lgkmcnt(6)" ::: "memory");
}
static __device__ __forceinline__ void lgkm0() {
  asm volatile("s_waitcnt lgkmcnt(0)" ::: "memory");
}
// raw LDS read: we own the lgkmcnt discipline
static __device__ __forceinline__ f32x4 ds128(unsigned addr) {
  f32x4 d;
  asm volatile("ds_read_b128 %0, %1" : "=&v"(d) : "v"(addr));
  return d;
}

// ---------------- f32 -> bf16 straight convert (x) ----------------
__global__ __launch_bounds__(256)
void convert_kernel(const float* __restrict__ in, unsigned short* __restrict__ out, size_t n)
{
  size_t i = ((size_t)blockIdx.x * blockDim.x + threadIdx.x) * 8;
  if (i >= n) return;
  float4 a = *(const float4*)(in + i);
  float4 b = *(const float4*)(in + i + 4);
  u16x8 o;
  o[0] = f2bf(a.x); o[1] = f2bf(a.y); o[2] = f2bf(a.z); o[3] = f2bf(a.w);
  o[4] = f2bf(b.x); o[5] = f2bf(b.y); o[6] = f2bf(b.z); o[7] = f2bf(b.w);
  *(u16x8*)(out + i) = o;
}

// ---- f32 [E][Ks][Ns] -> bf16 [E][Ns][Ks] transpose-convert, 64x64 tiles ----
// Loads: 256B/wave coalesced. Stores: per-4-lane group covers one full out-row
// segment of 64 bf16 = 128B contiguous (2 x u16x8 per thread).
// LDS bank check (65*stride ≡ 1 mod 32): store-phase reads hit each bank 2x
// per wave = free (m136).
__global__ __launch_bounds__(256)
void transpose64_kernel(const float* __restrict__ in, unsigned short* __restrict__ out,
                        int Ks, int Ns)
{
  __shared__ float tile[64][65];
  const int e = blockIdx.z;
  const int nx = Ns >> 6;
  const int bx = blockIdx.x % nx, by = blockIdx.x / nx;
  const float* ip = in + (size_t)e * Ks * Ns;
  unsigned short* op = out + (size_t)e * Ks * Ns;
  const int c0 = bx * 64, r0 = by * 64;
  const int tid = threadIdx.x;
  const int lc = tid & 63, lr = tid >> 6;

#pragma unroll
  for (int i = 0; i < 16; ++i)
    tile[lr + 4 * i][lc] = ip[(size_t)(r0 + lr + 4 * i) * Ns + c0 + lc];
  __syncthreads();

  const int c  = tid >> 2;          // out row (global col) 0..63
  const int ks = (tid & 3) * 16;    // k-offset 0,16,32,48
  u16x8 o0, o1;
#pragma unroll
  for (int j = 0; j < 8; ++j) o0[j] = f2bf(tile[ks + j][c]);
#pragma unroll
  for (int j = 0; j < 8; ++j) o1[j] = f2bf(tile[ks + 8 + j][c]);
  unsigned short* dst = op + (size_t)(c0 + c) * Ks + r0 + ks;
  *(u16x8*)dst = o0;
  *(u16x8*)(dst + 8) = o1;
}

// ======== grouped GEMM, 256x256 tile, BK=64, 32x32x16 MFMA (r11 verbatim) ====
// Best measured configuration (r11: fused 427us/883TF). XCD chunking: each XCD
// owns 16 consecutive row-tiles x all column tiles (FETCH 811->484MB proven).
// asm-DS 4-cluster pipeline, counted lgkm, 1 barrier/tile.
// MODE 0: fused gate+up, B cols interleaved by 32 (g/u): h = bf16(silu(g)*u).
// MODE 1: down: Cf = acc (f32).
template<int MODE, int K, int N>
__global__ __launch_bounds__(512, 2)
void gemm_kernel(const unsigned short* __restrict__ A,
                 const unsigned short* __restrict__ B0m,
                 const unsigned short* __restrict__ B1m,
                 unsigned short* __restrict__ Hc,
                 float* __restrict__ Cf,
                 const int* __restrict__ gs)
{
  constexpr int NRT = TOKENS / BM;   // 128 row tiles
  constexpr int nt  = K / BK;

  __shared__ __align__(16) unsigned short lA[2][256 * 64];  // 64 KiB
  __shared__ __align__(16) unsigned short lB[2][256 * 64];  // 64 KiB

  const int xcd = blockIdx.x & 7;
  const int i   = blockIdx.x >> 3;
  const int rt  = xcd * (NRT / 8) + (i % (NRT / 8));
  const int ct  = i / (NRT / 8);
  const int row0 = rt * BM;

  int e = 0;
  { int a0 = 0;
    for (int ii = 0; ii < NEXP; ++ii) { int s = gs[ii]; if (row0 < a0 + s) { e = ii; break; } a0 += s; } }

  const unsigned short* Ap = A + (size_t)row0 * K;
  const unsigned short* Bg = B0m + (size_t)e * N * K;
  const unsigned short* Bu = (MODE == 0) ? (B1m + (size_t)e * N * K) : nullptr;

  const int tid  = threadIdx.x;
  const int lane = tid & 63, wave = tid >> 6;
  const int wr = wave >> 2, wc = wave & 3;   // 2 M-waves x 4 N-waves, 128x64/wave
  const int l31 = lane & 31, hi = lane >> 5, l7 = lane & 7;
  const int r8 = lane >> 3;
  const int slog = ((lane & 7) ^ r8) * 8;    // pre-swizzled staging source column

  const unsigned sw0 = (unsigned)(((0 + hi) ^ l7) * 16);
  const unsigned sw1 = (unsigned)(((2 + hi) ^ l7) * 16);
  const unsigned sw2 = (unsigned)(((4 + hi) ^ l7) * 16);
  const unsigned sw3 = (unsigned)(((6 + hi) ^ l7) * 16);

  const unsigned lAb = (unsigned)(unsigned long long)(const void*)&lA[0][0];
  const unsigned lBb = (unsigned)(unsigned long long)(const void*)&lB[0][0];
  const unsigned aRow = lAb + (unsigned)((wr * 128 + l31) * 128);  // row stride 128B
  const unsigned bRow = lBb + (unsigned)((wc * 64 + l31) * 128);

  f32x16 acc[4][2] = {};

  auto stage = [&](int chunk, int tt) {
    const int buf = tt & 1;
    const int k0 = tt * BK;
#pragma unroll
    for (int w = 0; w < 2; ++w) {
      if (chunk >= 2) {
        const int c = chunk - 2;
        unsigned short* ldst = &lA[buf][(c * 128 + w * 64 + wave * 8) * 64];
        const int grow = c * 128 + w * 64 + wave * 8 + r8;
        gload16(Ap + (size_t)grow * K + k0 + slog, ldst);
      } else {
        unsigned short* ldst = &lB[buf][(chunk * 128 + w * 64 + wave * 8) * 64];
        const int rem = w * 64 + wave * 8 + r8;       // 0..127
        const int v = chunk * 128 + rem;              // B LDS row 0..255
        if constexpr (MODE == 0) {
          const int wcq = v >> 6, p = (v >> 5) & 1, ii = v & 31;
          const unsigned short* mb = p ? Bu : Bg;
          const int gcol = ct * 128 + wcq * 32 + ii;
          gload16(mb + (size_t)gcol * K + k0 + slog, ldst);
        } else {
          const int gcol = ct * 256 + v;
          gload16(Bg + (size_t)gcol * K + k0 + slog, ldst);
        }
      }
    }
  };

  auto rdA = [&](f32x4* d, unsigned sw, unsigned bufoff) {
#pragma unroll
    for (int m = 0; m < 4; ++m)
      d[m] = ds128(aRow + bufoff + (unsigned)(m * 4096) + sw);
  };
  auto rdB = [&](f32x4* d, unsigned sw, unsigned bufoff) {
    d[0] = ds128(bRow + bufoff + sw);
    d[1] = ds128(bRow + bufoff + 4096u + sw);
  };
  auto cluster = [&](const f32x4* a4, const f32x4* b2) {
    __builtin_amdgcn_sched_barrier(0);
    __builtin_amdgcn_s_setprio(1);
#pragma unroll
    for (int m = 0; m < 4; ++m)
#pragma unroll
      for (int n2 = 0; n2 < 2; ++n2)
        acc[m][n2] = __builtin_amdgcn_mfma_f32_32x32x16_bf16(
            __builtin_bit_cast(bf16x8, a4[m]), __builtin_bit_cast(bf16x8, b2[n2]),
            acc[m][n2], 0, 0, 0);
    __builtin_amdgcn_s_setprio(0);
    __builtin_amdgcn_sched_barrier(0);
  };

  // prologue: tile 0 staged and published
  stage(0, 0); stage(1, 0); stage(2, 0); stage(3, 0);
  vwait0();
  __builtin_amdgcn_s_barrier();

  f32x4 aS0[4], bS0[2], aS1[4], bS1[2], aS2[4], bS2[2];

#pragma unroll 1
  for (int t = 0; t < nt; ++t) {
    const unsigned bufoff = (unsigned)((t & 1) * 32768);
    const bool more = (t + 1 < nt);

    rdA(aS0, sw0, bufoff); rdB(bS0, sw0, bufoff);   // kk0
    rdA(aS1, sw1, bufoff); rdB(bS1, sw1, bufoff);   // kk1
    lgkm6();                                        // kk0 complete, kk1 in flight
    cluster(aS0, bS0);
    if (more) { stage(0, t + 1); stage(1, t + 1); }
    rdA(aS2, sw2, bufoff); rdB(bS2, sw2, bufoff);   // kk2
    lgkm6();                                        // kk1 complete
    cluster(aS1, bS1);
    if (more) { stage(2, t + 1); stage(3, t + 1); }
    rdA(aS0, sw3, bufoff); rdB(bS0, sw3, bufoff);   // kk3 (reuse set 0)
    lgkm6();                                        // kk2 complete
    cluster(aS2, bS2);
    lgkm0();                                        // kk3 complete
    cluster(aS0, bS0);

    vwait0();                                       // own t+1 stages landed
    __builtin_amdgcn_s_barrier();                   // publish LDS[t+1 buffer]
  }

  // epilogue. 32x32 C/D layout (m74/m101): col = lane&31,
  // row = (reg&3) + 8*(reg>>2) + 4*(lane>>5)
#pragma unroll
  for (int m = 0; m < 4; ++m) {
    const int rowb = row0 + wr * 128 + m * 32 + 4 * hi;
    if constexpr (MODE == 0) {
      const int col = ct * 128 + wc * 32 + l31;
      f32x16 g = acc[m][0], u = acc[m][1];
#pragma unroll
      for (int r = 0; r < 16; ++r) {
        const int row = rowb + (r & 3) + 8 * (r >> 2);
        float gv = g[r];
        float s = gv / (1.f + __expf(-gv)) * u[r];
        Hc[(size_t)row * N + col] = f2bf(s);
      }
    } else {
#pragma unroll
      for (int n2 = 0; n2 < 2; ++n2) {
        const int col = ct * 256 + wc * 64 + n2 * 32 + l31;
        f32x16 v = acc[m][n2];
#pragma unroll
        for (int r = 0; r < 16; ++r) {
          const int row = rowb + (r & 3) + 8 * (r >> 2);
          Cf[(size_t)row * N + col] = v[r];
        }
      }
    }
  }
}

extern "C" void kernel_launch(void* const* d_in, const int* in_sizes, int n_in,
                              void* d_out, int out_size, void* d_ws, size_t ws_size,
                              hipStream_t stream)
{
  const float* x  = (const float*)d_in[0];
  const float* wg = (const float*)d_in[1];
  const float* wu = (const float*)d_in[2];
  const float* wd = (const float*)d_in[3];
  const int*   gs = (const int*)d_in[4];
  float* out = (float*)d_out;

  const size_t SZ_XB = (size_t)TOKENS * HID * 2;
  const size_t SZ_W  = (size_t)NEXP * HID * IMD * 2;
  const size_t SZ_H  = (size_t)TOKENS * IMD * 2;
  if (ws_size < SZ_XB + 2 * SZ_W + SZ_H) return;

  char* ws = (char*)d_ws;
  unsigned short* xb  = (unsigned short*)ws;
  unsigned short* wTg = (unsigned short*)(ws + SZ_XB);
  unsigned short* wTu = (unsigned short*)(ws + SZ_XB + SZ_W);
  unsigned short* h   = (unsigned short*)(ws + SZ_XB + 2 * SZ_W);

  const int cvt_grid = (int)(((size_t)TOKENS * HID) / (256 * 8));
  convert_kernel<<<cvt_grid, 256, 0, stream>>>(x, xb, (size_t)TOKENS * HID);

  // 64x64 transposes: wg/wu (Ks=HID, Ns=IMD): grid.x = 22*32 = 704
  transpose64_kernel<<<dim3((IMD / 64) * (HID / 64), 1, NEXP), 256, 0, stream>>>(
      wg, wTg, HID, IMD);
  transpose64_kernel<<<dim3((IMD / 64) * (HID / 64), 1, NEXP), 256, 0, stream>>>(
      wu, wTu, HID, IMD);
  gemm_kernel<0, HID, IMD><<<(TOKENS / BM) * (IMD / 128), 512, 0, stream>>>(
      xb, wTg, wTu, h, nullptr, gs);

  // wd (Ks=IMD, Ns=HID): grid.x = 32*22 = 704; reuses wTg
  transpose64_kernel<<<dim3((HID / 64) * (IMD / 64), 1, NEXP), 256, 0, stream>>>(
      wd, wTg, IMD, HID);
  gemm_kernel<1, IMD, HID><<<(TOKENS / BM) * (HID / 256), 512, 0, stream>>>(
      h, wTg, nullptr, nullptr, out, gs);
}